// Round 7
// baseline (238.988 us; speedup 1.0000x reference)
//
#include <hip/hip_runtime.h>
#include <hip/hip_bf16.h>

#define C_IN   256
#define C_OUT  512
#define NFILT  4

#define BM 128
#define BN 128
#define BK 32
#define SAS 40   // fallback-path LDS row stride

// fast path: 32-wide K-steps, 8 steps, ring of 3 LDS buffers, A staged as fp32
#define NSTEP 8

typedef __attribute__((ext_vector_type(8))) short bf16x8;
typedef __attribute__((ext_vector_type(4))) float floatx4;

union Pack8 { uint4 u; __hip_bfloat16 h[8]; };

// ---- bucketize: per-block LDS histogram, 4 global atomics per block ----
__global__ __launch_bounds__(1024) void bucketize_kernel(
    const float* __restrict__ xyz, int* __restrict__ idxbuf,
    int* __restrict__ cnt, int P)
{
    __shared__ int hist[NFILT];        // block totals
    __shared__ int wbase[16][NFILT];   // per-wave base within block
    __shared__ int gbase[NFILT];       // block's global base per filter

    int tid = threadIdx.x;
    int wid = tid >> 6;
    int lane = tid & 63;
    if (tid < NFILT) hist[tid] = 0;
    __syncthreads();

    int pid = blockIdx.x * 1024 + tid;
    int filt = -1;
    if (pid < P) {
        float x = xyz[pid * 3 + 0];
        float y = xyz[pid * 3 + 1];
        float z = xyz[pid * 3 + 2];
        // match np: non-fused fp32 sum of squares, then sqrt, then strict <
        float r2 = __fadd_rn(__fadd_rn(__fmul_rn(x, x), __fmul_rn(y, y)), __fmul_rn(z, z));
        float r = sqrtf(r2);
        if (r < 1.0f)        filt = 0;
        else if (r < 1.5f)   filt = 1;
        else if (r < 2.0f)   filt = 2;
        else if (r < 100.0f) filt = 3;
        else                 filt = 0;   // argmax over all-false booleans returns 0
    }

    int myoff = 0;
#pragma unroll
    for (int f = 0; f < NFILT; ++f) {
        unsigned long long m = __ballot(filt == f);
        if (lane == 0) wbase[wid][f] = atomicAdd(&hist[f], (int)__popcll(m));
        if (filt == f) myoff = __popcll(m & ((1ull << lane) - 1ull));
    }
    __syncthreads();
    if (tid < NFILT) gbase[tid] = atomicAdd(&cnt[tid], hist[tid]);
    __syncthreads();

    if (filt >= 0)
        idxbuf[filt * P + gbase[filt] + wbase[wid][filt] + myoff] = pid;
}

// also zeroes cnt (runs before bucketize on the same stream)
__global__ void convert_w_kernel(const float* __restrict__ w,
                                 ushort* __restrict__ wb,
                                 int* __restrict__ cnt) {
    if (blockIdx.x == 0 && threadIdx.x < NFILT) cnt[threadIdx.x] = 0;
    int i = (blockIdx.x * blockDim.x + threadIdx.x) * 4;
    float4 v = *(const float4*)(w + i);
    union { ushort4 u; __hip_bfloat16 h[4]; } cv;
    cv.h[0] = __float2bfloat16(v.x);
    cv.h[1] = __float2bfloat16(v.y);
    cv.h[2] = __float2bfloat16(v.z);
    cv.h[3] = __float2bfloat16(v.w);
    *(ushort4*)(wb + i) = cv.u;
}

// ---- fused staging: A (fp32, pid-scattered rows via sIdx) + B (bf16) ----
// A: 16 KB/step = 16 segs of 1 KB (8 rows x 128 B). Lane l covers row
//    seg*8 + (l>>3), chunk-slot l&7; source chunk pre-swizzled
//    c = (l&7) ^ ((l>>3)&7) (involution, 8-row period). Per-lane GLOBAL
//    address carries the pid scatter (gload_lds dest is uniform+lane*16).
// B: 8 KB/step = 8 segs of 1 KB (16 rows x 64 B). Lane l covers row
//    seg*16 + (l>>2), chunk-slot l&3; source chunk c = (l&3) ^ ((l>>3)&3).
#define STAGE_AB(s, b) do {                                                     \
    int kByteA = (s) * 128;                                                     \
    int kByteB = (s) * 64;                                                      \
    _Pragma("unroll")                                                           \
    for (int n = 0; n < 4; ++n) {                                               \
        int seg = wid * 4 + n;                                                  \
        const char* srcA = (const char*)feat                                    \
            + ((size_t)sIdxv[n] * (C_IN * 4)) + kByteA + aschunk * 16;          \
        __builtin_amdgcn_global_load_lds(                                       \
            (const __attribute__((address_space(1))) void*)srcA,                \
            (__attribute__((address_space(3))) void*)&sAf[b][seg * 256], 16, 0, 0); \
    }                                                                           \
    _Pragma("unroll")                                                           \
    for (int n = 0; n < 2; ++n) {                                               \
        int seg = wid * 2 + n;                                                  \
        int row = seg * 16 + (lane >> 2);                                       \
        const char* srcB = bBase + ((size_t)(wRow0 + row) * (C_IN * 2))         \
                                 + kByteB + bschunk * 16;                       \
        __builtin_amdgcn_global_load_lds(                                       \
            (const __attribute__((address_space(1))) void*)srcB,                \
            (__attribute__((address_space(3))) void*)&sBb[b][seg * 512], 16, 0, 0); \
    }                                                                           \
} while (0)

// fused grouped GEMM: A read directly from feat (fp32->bf16 after LDS read),
// ring-3 buffers, depth-2 stage issue, counted vmcnt (6 loads/stage/wave),
// one barrier per K-step. 73 KB LDS -> 2 blocks/CU.
__global__ __launch_bounds__(256, 2) void gemm_fast_kernel(
    const float* __restrict__ feat, const ushort* __restrict__ wb,
    const float* __restrict__ bias, const int* __restrict__ idxbuf,
    const int* __restrict__ cnt, float* __restrict__ out, int P)
{
    __shared__ float  sAf[3][BM * 32];   // 3 x 16 KB fp32 A ring (linear dest)
    __shared__ ushort sBb[3][BN * 32];   // 3 x  8 KB bf16 B ring
    __shared__ int    sIdx[BM];
    __shared__ float  sBias[BN];

    // XCD-aware swizzle: 4 col-tiles of one row-tile land consecutively in
    // one XCD's round-robin stream. gridDim.x == 4, gridDim.y % 8 == 0.
    int lid = blockIdx.x + (blockIdx.y << 2);
    int g = lid & 7;
    int q = lid >> 3;
    int cTile = q & 3;
    int t = ((q >> 2) << 3) + g;

    int c0 = cnt[0], c1 = cnt[1], c2 = cnt[2], c3 = cnt[3];
    int counts[4] = {c0, c1, c2, c3};
    int f = -1, lt = 0;
    for (int ff = 0; ff < 4; ++ff) {
        int nt = (counts[ff] + BM - 1) / BM;
        if (t < nt) { f = ff; lt = t; break; }
        t -= nt;
    }
    if (f < 0) return;

    int tid = threadIdx.x;
    int oBase = cTile * BN;
    int cn = counts[f];
    int wRow0 = f * C_OUT + oBase;        // first weight row of this tile

    int wid = tid >> 6;
    int lane = tid & 63;
    int wm = (wid >> 1) * 64;
    int wn = (wid & 1) * 64;
    int lcol = lane & 15;
    int quad = lane >> 4;

    // read-side swizzles (lane-constant; wm, i*16, wn, j*16 are 0 mod 8/16)
    int am = lcol & 7;                          // A: 8-chunk involution key
    int rchunkB = (quad ^ ((lcol >> 1) & 3)) * 8;   // B: as R5 (verified)

    // staging source pre-swizzles
    int aschunk = (lane & 7) ^ ((lane >> 3) & 7);
    int bschunk = (lane & 3) ^ ((lane >> 3) & 3);

    const char* bBase = (const char*)wb;

    // prologue: publish sIdx/sBias, then preload this lane's 4 A-row pids,
    // then issue stages 0 and 1.
    if (tid < BM) {
        int r = lt * BM + tid;
        sIdx[tid] = (r < cn) ? idxbuf[f * P + r] : -1;
    }
    if (tid < BN) sBias[tid] = bias[f * C_OUT + oBase + tid];
    __syncthreads();

    int sIdxv[4];
#pragma unroll
    for (int n = 0; n < 4; ++n) {
        int r = wid * 32 + n * 8 + (lane >> 3);   // row this lane stages in seg n
        int v = sIdx[r];
        sIdxv[n] = (v < 0) ? 0 : v;               // clamp pad rows; masked at store
    }

    STAGE_AB(0, 0);
    STAGE_AB(1, 1);

    floatx4 acc[4][4];
#pragma unroll
    for (int i = 0; i < 4; ++i)
#pragma unroll
        for (int j = 0; j < 4; ++j)
            acc[i][j] = (floatx4){0.f, 0.f, 0.f, 0.f};

#pragma unroll
    for (int s = 0; s < NSTEP; ++s) {
        // certify OWN stage-s loads landed (6 loads per outstanding stage);
        // stage s+1 stays in flight (counted vmcnt — never drain mid-loop).
        if (s < NSTEP - 1) asm volatile("s_waitcnt vmcnt(6)" ::: "memory");
        else               asm volatile("s_waitcnt vmcnt(0)" ::: "memory");
        // after this barrier: every wave's stage-s data is in LDS, and every
        // wave has finished its step-(s-1) ds_reads -> buf (s+2)%3 is free.
        __builtin_amdgcn_s_barrier();
        __builtin_amdgcn_sched_barrier(0);   // barrier builtin is not a fence

        if (s + 2 < NSTEP) STAGE_AB(s + 2, (s + 2) % 3);

        const float*  cA = sAf[s % 3];
        const ushort* cB = sBb[s % 3];

        bf16x8 af[4], bfr[4];
#pragma unroll
        for (int i = 0; i < 4; ++i) {
            int r = wm + i * 16 + lcol;
            int p0 = (2 * quad) ^ am;
            int p1 = (2 * quad + 1) ^ am;
            float4 f0 = *(const float4*)&cA[r * 32 + p0 * 4];
            float4 f1 = *(const float4*)&cA[r * 32 + p1 * 4];
            Pack8 pk;
            pk.h[0] = __float2bfloat16(f0.x); pk.h[1] = __float2bfloat16(f0.y);
            pk.h[2] = __float2bfloat16(f0.z); pk.h[3] = __float2bfloat16(f0.w);
            pk.h[4] = __float2bfloat16(f1.x); pk.h[5] = __float2bfloat16(f1.y);
            pk.h[6] = __float2bfloat16(f1.z); pk.h[7] = __float2bfloat16(f1.w);
            af[i] = *reinterpret_cast<bf16x8*>(&pk);
        }
#pragma unroll
        for (int j = 0; j < 4; ++j)
            bfr[j] = *(const bf16x8*)&cB[(wn + j * 16 + lcol) * 32 + rchunkB];
#pragma unroll
        for (int i = 0; i < 4; ++i)
#pragma unroll
            for (int j = 0; j < 4; ++j)
                acc[i][j] = __builtin_amdgcn_mfma_f32_16x16x32_bf16(af[i], bfr[j], acc[i][j], 0, 0, 0);
        // ds_read results are consumed by cvt/MFMA before the next barrier
        // (compiler-inserted lgkm waits), so buffer release is safe.
    }

    // epilogue: scatter rows by original point id, add bias
#pragma unroll
    for (int i = 0; i < 4; ++i) {
        int r0 = wm + i * 16 + quad * 4;
        int pid0 = sIdx[r0 + 0];
        int pid1 = sIdx[r0 + 1];
        int pid2 = sIdx[r0 + 2];
        int pid3 = sIdx[r0 + 3];
#pragma unroll
        for (int j = 0; j < 4; ++j) {
            int o = oBase + wn + j * 16 + lcol;
            float bv = sBias[wn + j * 16 + lcol];
            if (pid0 >= 0) out[pid0 * C_OUT + o] = acc[i][j][0] + bv;
            if (pid1 >= 0) out[pid1 * C_OUT + o] = acc[i][j][1] + bv;
            if (pid2 >= 0) out[pid2 * C_OUT + o] = acc[i][j][2] + bv;
            if (pid3 >= 0) out[pid3 * C_OUT + o] = acc[i][j][3] + bv;
        }
    }
}

// ---------------- fallback (old fused) gemm, used only if ws too small ----
__global__ __launch_bounds__(256) void gemm_kernel(
    const float* __restrict__ feat, const ushort* __restrict__ wb,
    const float* __restrict__ bias, const int* __restrict__ idxbuf,
    const int* __restrict__ cnt, float* __restrict__ out, int P)
{
    __shared__ ushort sA[BM * SAS];
    __shared__ ushort sB[BN * SAS];
    __shared__ int    sIdx[BM];
    __shared__ float  sBias[BN];

    int lid = blockIdx.x + (blockIdx.y << 2);
    int g = lid & 7;
    int q = lid >> 3;
    int cTile = q & 3;
    int t = ((q >> 2) << 3) + g;

    int counts[4];
    counts[0] = cnt[0]; counts[1] = cnt[1]; counts[2] = cnt[2]; counts[3] = cnt[3];
    int f = -1, lt = 0;
    for (int ff = 0; ff < 4; ++ff) {
        int nt = (counts[ff] + BM - 1) / BM;
        if (t < nt) { f = ff; lt = t; break; }
        t -= nt;
    }
    if (f < 0) return;

    int tid = threadIdx.x;
    int oBase = cTile * BN;
    int rowBase = lt * BM;
    int cn = counts[f];

    if (tid < BM) {
        int r = rowBase + tid;
        sIdx[tid] = (r < cn) ? idxbuf[f * P + r] : -1;
    }
    if (tid < BN) sBias[tid] = bias[f * C_OUT + oBase + tid];
    __syncthreads();

    int sRow = tid >> 1;
    int sHalf = tid & 1;
    int myIdx = sIdx[sRow];
    const float* aRow = feat + (size_t)(myIdx < 0 ? 0 : myIdx) * C_IN + sHalf * 16;
    const ushort* bRow = wb + (size_t)(f * C_OUT + oBase + sRow) * C_IN + sHalf * 16;

    int wid = tid >> 6;
    int lane = tid & 63;
    int wm = (wid >> 1) * 64;
    int wn = (wid & 1) * 64;
    int lcol = lane & 15;
    int quad = lane >> 4;

    floatx4 acc[4][4];
#pragma unroll
    for (int i = 0; i < 4; ++i)
#pragma unroll
        for (int j = 0; j < 4; ++j)
            acc[i][j] = (floatx4){0.f, 0.f, 0.f, 0.f};

    for (int kk = 0; kk < C_IN; kk += BK) {
        const float* ap = aRow + kk;
        float4 a0 = *(const float4*)(ap + 0);
        float4 a1 = *(const float4*)(ap + 4);
        float4 a2 = *(const float4*)(ap + 8);
        float4 a3 = *(const float4*)(ap + 12);
        const ushort* bp = bRow + kk;
        uint4 b01 = *(const uint4*)(bp + 0);
        uint4 b23 = *(const uint4*)(bp + 8);

        Pack8 p0, p1;
        p0.h[0] = __float2bfloat16(a0.x); p0.h[1] = __float2bfloat16(a0.y);
        p0.h[2] = __float2bfloat16(a0.z); p0.h[3] = __float2bfloat16(a0.w);
        p0.h[4] = __float2bfloat16(a1.x); p0.h[5] = __float2bfloat16(a1.y);
        p0.h[6] = __float2bfloat16(a1.z); p0.h[7] = __float2bfloat16(a1.w);
        p1.h[0] = __float2bfloat16(a2.x); p1.h[1] = __float2bfloat16(a2.y);
        p1.h[2] = __float2bfloat16(a2.z); p1.h[3] = __float2bfloat16(a2.w);
        p1.h[4] = __float2bfloat16(a3.x); p1.h[5] = __float2bfloat16(a3.y);
        p1.h[6] = __float2bfloat16(a3.z); p1.h[7] = __float2bfloat16(a3.w);

        ushort* dA = &sA[sRow * SAS + sHalf * 16];
        *(uint4*)(dA + 0) = p0.u;
        *(uint4*)(dA + 8) = p1.u;
        ushort* dB = &sB[sRow * SAS + sHalf * 16];
        *(uint4*)(dB + 0) = b01;
        *(uint4*)(dB + 8) = b23;

        __syncthreads();

        bf16x8 af[4], bfr[4];
#pragma unroll
        for (int i = 0; i < 4; ++i)
            af[i] = *(const bf16x8*)&sA[(wm + i * 16 + lcol) * SAS + quad * 8];
#pragma unroll
        for (int j = 0; j < 4; ++j)
            bfr[j] = *(const bf16x8*)&sB[(wn + j * 16 + lcol) * SAS + quad * 8];
#pragma unroll
        for (int i = 0; i < 4; ++i)
#pragma unroll
            for (int j = 0; j < 4; ++j)
                acc[i][j] = __builtin_amdgcn_mfma_f32_16x16x32_bf16(af[i], bfr[j], acc[i][j], 0, 0, 0);

        __syncthreads();
    }

#pragma unroll
    for (int i = 0; i < 4; ++i) {
        int r0 = wm + i * 16 + quad * 4;
        int pid0 = sIdx[r0 + 0];
        int pid1 = sIdx[r0 + 1];
        int pid2 = sIdx[r0 + 2];
        int pid3 = sIdx[r0 + 3];
#pragma unroll
        for (int j = 0; j < 4; ++j) {
            int o = oBase + wn + j * 16 + lcol;
            float bv = sBias[wn + j * 16 + lcol];
            if (pid0 >= 0) out[pid0 * C_OUT + o] = acc[i][j][0] + bv;
            if (pid1 >= 0) out[pid1 * C_OUT + o] = acc[i][j][1] + bv;
            if (pid2 >= 0) out[pid2 * C_OUT + o] = acc[i][j][2] + bv;
            if (pid3 >= 0) out[pid3 * C_OUT + o] = acc[i][j][3] + bv;
        }
    }
}

extern "C" void kernel_launch(void* const* d_in, const int* in_sizes, int n_in,
                              void* d_out, int out_size, void* d_ws, size_t ws_size,
                              hipStream_t stream) {
    const float* feat = (const float*)d_in[0];
    const float* xyz  = (const float*)d_in[1];
    const float* w    = (const float*)d_in[2];
    const float* bias = (const float*)d_in[3];
    float* out = (float*)d_out;
    int P = in_sizes[0] / C_IN;

    char* ws = (char*)d_ws;
    size_t offIdx = 0;
    size_t offCnt = (size_t)4 * P * 4;
    size_t offWb  = offCnt + 16;
    size_t needed = offWb + (size_t)NFILT * C_OUT * C_IN * 2;

    int* idxbuf = (int*)(ws + offIdx);
    int* cntp   = (int*)(ws + offCnt);
    ushort* wb  = (ushort*)(ws + offWb);

    // convert_w also zeroes cnt; stream order guarantees visibility
    convert_w_kernel<<<(NFILT * C_OUT * C_IN) / 1024, 256, 0, stream>>>(w, wb, cntp);
    bucketize_kernel<<<(P + 1023) / 1024, 1024, 0, stream>>>(xyz, idxbuf, cntp, P);

    int tilesY = ((P / BM + NFILT + 7) / 8) * 8;   // padded so XCD swizzle is bijective
    dim3 grid(C_OUT / BN, tilesY);

    if (ws_size >= needed) {
        gemm_fast_kernel<<<grid, 256, 0, stream>>>(feat, wb, bias, idxbuf, cntp, out, P);
    } else {
        gemm_kernel<<<grid, 256, 0, stream>>>(feat, wb, bias, idxbuf, cntp, out, P);
    }
}

// Round 8
// 236.553 us; speedup vs baseline: 1.0103x; 1.0103x over previous
//
#include <hip/hip_runtime.h>
#include <hip/hip_bf16.h>

#define C_IN   256
#define C_OUT  512
#define NFILT  4

#define BM 128
#define BN 128
#define BK 32
#define SAS 40   // fallback-path LDS row stride

#define ST 36    // fast-path LDS row stride in ushorts (72 B): 16B-aligned, ~2-way banks

typedef __attribute__((ext_vector_type(8))) short bf16x8;
typedef __attribute__((ext_vector_type(4))) float floatx4;

union Pack8 { uint4 u; __hip_bfloat16 h[8]; };

// ---- bucketize: per-block LDS histogram, 4 global atomics per block ----
__global__ __launch_bounds__(1024) void bucketize_kernel(
    const float* __restrict__ xyz, int* __restrict__ idxbuf,
    int* __restrict__ cnt, int P)
{
    __shared__ int hist[NFILT];        // block totals
    __shared__ int wbase[16][NFILT];   // per-wave base within block
    __shared__ int gbase[NFILT];       // block's global base per filter

    int tid = threadIdx.x;
    int wid = tid >> 6;
    int lane = tid & 63;
    if (tid < NFILT) hist[tid] = 0;
    __syncthreads();

    int pid = blockIdx.x * 1024 + tid;
    int filt = -1;
    if (pid < P) {
        float x = xyz[pid * 3 + 0];
        float y = xyz[pid * 3 + 1];
        float z = xyz[pid * 3 + 2];
        // match np: non-fused fp32 sum of squares, then sqrt, then strict <
        float r2 = __fadd_rn(__fadd_rn(__fmul_rn(x, x), __fmul_rn(y, y)), __fmul_rn(z, z));
        float r = sqrtf(r2);
        if (r < 1.0f)        filt = 0;
        else if (r < 1.5f)   filt = 1;
        else if (r < 2.0f)   filt = 2;
        else if (r < 100.0f) filt = 3;
        else                 filt = 0;   // argmax over all-false booleans returns 0
    }

    int myoff = 0;
#pragma unroll
    for (int f = 0; f < NFILT; ++f) {
        unsigned long long m = __ballot(filt == f);
        if (lane == 0) wbase[wid][f] = atomicAdd(&hist[f], (int)__popcll(m));
        if (filt == f) myoff = __popcll(m & ((1ull << lane) - 1ull));
    }
    __syncthreads();
    if (tid < NFILT) gbase[tid] = atomicAdd(&cnt[tid], hist[tid]);
    __syncthreads();

    if (filt >= 0)
        idxbuf[filt * P + gbase[filt] + wbase[wid][filt] + myoff] = pid;
}

// also zeroes cnt (runs before bucketize on the same stream)
__global__ void convert_w_kernel(const float* __restrict__ w,
                                 ushort* __restrict__ wb,
                                 int* __restrict__ cnt) {
    if (blockIdx.x == 0 && threadIdx.x < NFILT) cnt[threadIdx.x] = 0;
    int i = (blockIdx.x * blockDim.x + threadIdx.x) * 4;
    float4 v = *(const float4*)(w + i);
    union { ushort4 u; __hip_bfloat16 h[4]; } cv;
    cv.h[0] = __float2bfloat16(v.x);
    cv.h[1] = __float2bfloat16(v.y);
    cv.h[2] = __float2bfloat16(v.z);
    cv.h[3] = __float2bfloat16(v.w);
    *(ushort4*)(wb + i) = cv.u;
}

// ---- full-N grouped GEMM: block = 128 rows x ALL 512 cols, 1024 threads ----
// 16 waves (4 row-groups x 4 col-groups), wave tile 32x128, acc 2x8 frags.
// A rows read ONCE system-wide (no col-tile redundancy); out rows written as
// one contiguous 2 KB per row by a single block; B (256 KB/block) L2-resident.
// Simple R0-style sync staging (empirically best across R0-R7).
__global__ __launch_bounds__(1024, 4) void gemm_fast_kernel(
    const float* __restrict__ feat, const ushort* __restrict__ wb,
    const float* __restrict__ bias, const int* __restrict__ idxbuf,
    const int* __restrict__ cnt, float* __restrict__ out, int P)
{
    __shared__ ushort sA[BM * ST];     //  9 KB
    __shared__ ushort sB[C_OUT * ST];  // 36 KB
    __shared__ int    sIdx[BM];
    __shared__ float  sBias[C_OUT];

    // linear block -> (bucket f, local row-tile lt)
    int t = blockIdx.x;
    int counts[4] = {cnt[0], cnt[1], cnt[2], cnt[3]};
    int f = -1, lt = 0;
    for (int ff = 0; ff < 4; ++ff) {
        int nt = (counts[ff] + BM - 1) / BM;
        if (t < nt) { f = ff; lt = t; break; }
        t -= nt;
    }
    if (f < 0) return;

    int tid = threadIdx.x;
    int cn = counts[f];

    if (tid < BM) {
        int r = lt * BM + tid;
        sIdx[tid] = (r < cn) ? idxbuf[f * P + r] : -1;
    }
    if (tid < C_OUT) sBias[tid] = bias[f * C_OUT + tid];
    __syncthreads();

    // staging assignment
    int ar = tid >> 3, aq = tid & 7;          // A: row 0..127, 16B f32 chunk 0..7
    int ap = sIdx[ar]; if (ap < 0) ap = 0;    // clamp pad rows (stores masked)
    const float* aSrc = feat + (size_t)ap * C_IN + aq * 4;
    int bc = tid >> 1, bh = tid & 1;          // B: col 0..511, 32B half 0..1
    const ushort* bSrc = wb + (size_t)(f * C_OUT + bc) * C_IN + bh * 16;

    // wave geometry
    int wid = tid >> 6, lane = tid & 63;
    int wm = (wid >> 2) * 32;                 // row base of this wave
    int wn = (wid & 3) * 128;                 // col base of this wave
    int lcol = lane & 15, quad = lane >> 4;

    floatx4 acc[2][8];
#pragma unroll
    for (int i = 0; i < 2; ++i)
#pragma unroll
        for (int j = 0; j < 8; ++j)
            acc[i][j] = (floatx4){0.f, 0.f, 0.f, 0.f};

    for (int kk = 0; kk < C_IN; kk += BK) {
        // stage A: 128 rows x 32 f32 -> bf16; this thread: 4 f32 of its row
        float4 av = *(const float4*)(aSrc + kk);
        union { ushort4 u; __hip_bfloat16 h[4]; } cv;
        cv.h[0] = __float2bfloat16(av.x);
        cv.h[1] = __float2bfloat16(av.y);
        cv.h[2] = __float2bfloat16(av.z);
        cv.h[3] = __float2bfloat16(av.w);
        *(ushort4*)&sA[ar * ST + aq * 4] = cv.u;
        // stage B: 512 cols x 32 bf16; this thread: 16 bf16 (32 B) of its col
        uint4 b0 = *(const uint4*)(bSrc + kk);
        uint4 b1 = *(const uint4*)(bSrc + kk + 8);
        *(uint4*)&sB[bc * ST + bh * 16 + 0] = b0;
        *(uint4*)&sB[bc * ST + bh * 16 + 8] = b1;
        __syncthreads();

        bf16x8 a0 = *(const bf16x8*)&sA[(wm + 0  + lcol) * ST + quad * 8];
        bf16x8 a1 = *(const bf16x8*)&sA[(wm + 16 + lcol) * ST + quad * 8];
#pragma unroll
        for (int jh = 0; jh < 2; ++jh) {      // B frags in 2 halves: VGPR cap
            bf16x8 bf[4];
#pragma unroll
            for (int j = 0; j < 4; ++j)
                bf[j] = *(const bf16x8*)&sB[(wn + (jh * 4 + j) * 16 + lcol) * ST + quad * 8];
#pragma unroll
            for (int j = 0; j < 4; ++j) {
                acc[0][jh * 4 + j] = __builtin_amdgcn_mfma_f32_16x16x32_bf16(a0, bf[j], acc[0][jh * 4 + j], 0, 0, 0);
                acc[1][jh * 4 + j] = __builtin_amdgcn_mfma_f32_16x16x32_bf16(a1, bf[j], acc[1][jh * 4 + j], 0, 0, 0);
            }
        }
        __syncthreads();
    }

    // epilogue: each row's full 512-col slice written by this block (4 waves),
    // contiguous 2 KB per row, scattered only at row granularity.
#pragma unroll
    for (int i = 0; i < 2; ++i) {
        int r0 = wm + i * 16 + quad * 4;
        int p0 = sIdx[r0 + 0];
        int p1 = sIdx[r0 + 1];
        int p2 = sIdx[r0 + 2];
        int p3 = sIdx[r0 + 3];
#pragma unroll
        for (int j = 0; j < 8; ++j) {
            int o = wn + j * 16 + lcol;
            float bv = sBias[o];
            if (p0 >= 0) out[(size_t)p0 * C_OUT + o] = acc[i][j][0] + bv;
            if (p1 >= 0) out[(size_t)p1 * C_OUT + o] = acc[i][j][1] + bv;
            if (p2 >= 0) out[(size_t)p2 * C_OUT + o] = acc[i][j][2] + bv;
            if (p3 >= 0) out[(size_t)p3 * C_OUT + o] = acc[i][j][3] + bv;
        }
    }
}

// ---------------- fallback (old fused) gemm, used only if ws too small ----
__global__ __launch_bounds__(256) void gemm_kernel(
    const float* __restrict__ feat, const ushort* __restrict__ wb,
    const float* __restrict__ bias, const int* __restrict__ idxbuf,
    const int* __restrict__ cnt, float* __restrict__ out, int P)
{
    __shared__ ushort sA[BM * SAS];
    __shared__ ushort sB[BN * SAS];
    __shared__ int    sIdx[BM];
    __shared__ float  sBias[BN];

    int lid = blockIdx.x + (blockIdx.y << 2);
    int g = lid & 7;
    int q = lid >> 3;
    int cTile = q & 3;
    int t = ((q >> 2) << 3) + g;

    int counts[4];
    counts[0] = cnt[0]; counts[1] = cnt[1]; counts[2] = cnt[2]; counts[3] = cnt[3];
    int f = -1, lt = 0;
    for (int ff = 0; ff < 4; ++ff) {
        int nt = (counts[ff] + BM - 1) / BM;
        if (t < nt) { f = ff; lt = t; break; }
        t -= nt;
    }
    if (f < 0) return;

    int tid = threadIdx.x;
    int oBase = cTile * BN;
    int rowBase = lt * BM;
    int cn = counts[f];

    if (tid < BM) {
        int r = rowBase + tid;
        sIdx[tid] = (r < cn) ? idxbuf[f * P + r] : -1;
    }
    if (tid < BN) sBias[tid] = bias[f * C_OUT + oBase + tid];
    __syncthreads();

    int sRow = tid >> 1;
    int sHalf = tid & 1;
    int myIdx = sIdx[sRow];
    const float* aRow = feat + (size_t)(myIdx < 0 ? 0 : myIdx) * C_IN + sHalf * 16;
    const ushort* bRow = wb + (size_t)(f * C_OUT + oBase + sRow) * C_IN + sHalf * 16;

    int wid = tid >> 6;
    int lane = tid & 63;
    int wm = (wid >> 1) * 64;
    int wn = (wid & 1) * 64;
    int lcol = lane & 15;
    int quad = lane >> 4;

    floatx4 acc[4][4];
#pragma unroll
    for (int i = 0; i < 4; ++i)
#pragma unroll
        for (int j = 0; j < 4; ++j)
            acc[i][j] = (floatx4){0.f, 0.f, 0.f, 0.f};

    for (int kk = 0; kk < C_IN; kk += BK) {
        const float* ap = aRow + kk;
        float4 a0 = *(const float4*)(ap + 0);
        float4 a1 = *(const float4*)(ap + 4);
        float4 a2 = *(const float4*)(ap + 8);
        float4 a3 = *(const float4*)(ap + 12);
        const ushort* bp = bRow + kk;
        uint4 b01 = *(const uint4*)(bp + 0);
        uint4 b23 = *(const uint4*)(bp + 8);

        Pack8 p0, p1;
        p0.h[0] = __float2bfloat16(a0.x); p0.h[1] = __float2bfloat16(a0.y);
        p0.h[2] = __float2bfloat16(a0.z); p0.h[3] = __float2bfloat16(a0.w);
        p0.h[4] = __float2bfloat16(a1.x); p0.h[5] = __float2bfloat16(a1.y);
        p0.h[6] = __float2bfloat16(a1.z); p0.h[7] = __float2bfloat16(a1.w);
        p1.h[0] = __float2bfloat16(a2.x); p1.h[1] = __float2bfloat16(a2.y);
        p1.h[2] = __float2bfloat16(a2.z); p1.h[3] = __float2bfloat16(a2.w);
        p1.h[4] = __float2bfloat16(a3.x); p1.h[5] = __float2bfloat16(a3.y);
        p1.h[6] = __float2bfloat16(a3.z); p1.h[7] = __float2bfloat16(a3.w);

        ushort* dA = &sA[sRow * SAS + sHalf * 16];
        *(uint4*)(dA + 0) = p0.u;
        *(uint4*)(dA + 8) = p1.u;
        ushort* dB = &sB[sRow * SAS + sHalf * 16];
        *(uint4*)(dB + 0) = b01;
        *(uint4*)(dB + 8) = b23;

        __syncthreads();

        bf16x8 af[4], bfr[4];
#pragma unroll
        for (int i = 0; i < 4; ++i)
            af[i] = *(const bf16x8*)&sA[(wm + i * 16 + lcol) * SAS + quad * 8];
#pragma unroll
        for (int j = 0; j < 4; ++j)
            bfr[j] = *(const bf16x8*)&sB[(wn + j * 16 + lcol) * SAS + quad * 8];
#pragma unroll
        for (int i = 0; i < 4; ++i)
#pragma unroll
            for (int j = 0; j < 4; ++j)
                acc[i][j] = __builtin_amdgcn_mfma_f32_16x16x32_bf16(af[i], bfr[j], acc[i][j], 0, 0, 0);

        __syncthreads();
    }

#pragma unroll
    for (int i = 0; i < 4; ++i) {
        int r0 = wm + i * 16 + quad * 4;
        int pid0 = sIdx[r0 + 0];
        int pid1 = sIdx[r0 + 1];
        int pid2 = sIdx[r0 + 2];
        int pid3 = sIdx[r0 + 3];
#pragma unroll
        for (int j = 0; j < 4; ++j) {
            int o = oBase + wn + j * 16 + lcol;
            float bv = sBias[wn + j * 16 + lcol];
            if (pid0 >= 0) out[pid0 * C_OUT + o] = acc[i][j][0] + bv;
            if (pid1 >= 0) out[pid1 * C_OUT + o] = acc[i][j][1] + bv;
            if (pid2 >= 0) out[pid2 * C_OUT + o] = acc[i][j][2] + bv;
            if (pid3 >= 0) out[pid3 * C_OUT + o] = acc[i][j][3] + bv;
        }
    }
}

extern "C" void kernel_launch(void* const* d_in, const int* in_sizes, int n_in,
                              void* d_out, int out_size, void* d_ws, size_t ws_size,
                              hipStream_t stream) {
    const float* feat = (const float*)d_in[0];
    const float* xyz  = (const float*)d_in[1];
    const float* w    = (const float*)d_in[2];
    const float* bias = (const float*)d_in[3];
    float* out = (float*)d_out;
    int P = in_sizes[0] / C_IN;

    char* ws = (char*)d_ws;
    size_t offIdx = 0;
    size_t offCnt = (size_t)4 * P * 4;
    size_t offWb  = offCnt + 16;
    size_t needed = offWb + (size_t)NFILT * C_OUT * C_IN * 2;

    int* idxbuf = (int*)(ws + offIdx);
    int* cntp   = (int*)(ws + offCnt);
    ushort* wb  = (ushort*)(ws + offWb);

    // convert_w also zeroes cnt; stream order guarantees visibility
    convert_w_kernel<<<(NFILT * C_OUT * C_IN) / 1024, 256, 0, stream>>>(w, wb, cntp);
    bucketize_kernel<<<(P + 1023) / 1024, 1024, 0, stream>>>(xyz, idxbuf, cntp, P);

    if (ws_size >= needed) {
        int tiles = P / BM + NFILT;   // worst-case tile count over all buckets
        gemm_fast_kernel<<<tiles, 1024, 0, stream>>>(feat, wb, bias, idxbuf, cntp, out, P);
    } else {
        int tilesY = ((P / BM + NFILT + 7) / 8) * 8;
        dim3 grid(C_OUT / BN, tilesY);
        gemm_kernel<<<grid, 256, 0, stream>>>(feat, wb, bias, idxbuf, cntp, out, P);
    }
}